// Round 12
// baseline (715.047 us; speedup 1.0000x reference)
//
#include <hip/hip_runtime.h>
#include <math.h>

// GLIFR (BNNFC) : B=32, T=1000, IN=256, H=512, OUT=128, A=2, DELAY=20
//  cvts: input->Abf (blocked bf16), W_iv/out_w -> blocked bf16, W_lat -> fp8
//  ph1: SYN = input @ W_iv          (bf16 MFMA GEMM, blocked operands)
//  ph2: 64 blocks = 2 per batch (n-split). Each block holds its 256-col W
//       slice fp8 IN LDS (128 KB, loaded once) -- R7-R11 proved the register
//       allocator will not keep W resident (all attempts = L2/scratch stream
//       at ~7 us/stage). Cross-block firing exchange via global fp8 slots +
//       agent-scope release/acquire flags (memset to 0 each launch).
//  ph3: out = F @ out_w + out_b     (bf16 MFMA GEMM)

constexpr int Bsz   = 32;
constexpr int Tn    = 1000;
constexpr int INn   = 256;
constexpr int Hn    = 512;
constexpr int OUTn  = 128;
constexpr int DELAY = 20;
constexpr int NBLK  = Tn / DELAY;   // 50
constexpr float DTc = 0.05f;
constexpr float Rc  = 0.1f;
constexpr int BH = Bsz * Hn;                  // 16384

typedef __attribute__((ext_vector_type(8))) short short8v;  // 8 bf16
typedef __attribute__((ext_vector_type(4))) float f32x4;

__device__ __forceinline__ float sigmoidf_(float x) {
    return 1.0f / (1.0f + expf(-x));
}
__device__ __forceinline__ float sigfast_(float x) {
    return __builtin_amdgcn_rcpf(1.0f + __builtin_amdgcn_exp2f(x * -1.44269504f));
}
__device__ __forceinline__ float bf2f(unsigned short u) {
    return __uint_as_float(((unsigned)u) << 16);
}
__device__ __forceinline__ unsigned short f2bf(float f) {
    unsigned x = __float_as_uint(f);
    return (unsigned short)((x + 0x7fff + ((x >> 16) & 1)) >> 16);  // RNE
}
// OCP e4m3fn encode, RNE, |x| small
__device__ __forceinline__ unsigned char f2e4m3(float x) {
    unsigned b = __float_as_uint(x);
    unsigned s = (b >> 31) << 7;
    b &= 0x7fffffffu;
    unsigned code;
    if (__uint_as_float(b) < 0.015625f) {
        code = (unsigned)__float2int_rn(__uint_as_float(b) * 512.0f);
    } else {
        unsigned r = b + 0x7ffffu + ((b >> 20) & 1);
        int e = (int)(r >> 23) - 127;
        code = (unsigned)(((e + 7) << 3) | ((r >> 20) & 7));
    }
    return (unsigned char)(s | code);
}
__device__ __forceinline__ void gl_lds16(const void* g, void* l) {
    __builtin_amdgcn_global_load_lds(
        (const __attribute__((address_space(1))) void*)g,
        (__attribute__((address_space(3))) void*)l, 16, 0, 0);
}

// ---------------------------------------------------------------------------
// input [B,T,IN] fp32 -> Abf blocked bf16 [mtile 250][kt 4][kq 8][row 128][e 8]
// ---------------------------------------------------------------------------
__global__ __launch_bounds__(256) void cvt_in(
    const float* __restrict__ in, unsigned short* __restrict__ Abf)
{
    __shared__ float t[128][65];
    const int tid = threadIdx.x;
    const int mtile = blockIdx.x >> 2, kt = blockIdx.x & 3;
    const int rr = tid >> 4, cc = (tid & 15) * 4;
#pragma unroll
    for (int j = 0; j < 8; ++j) {
        int row = j * 16 + rr;
        int m = mtile * 128 + row;
        float4 v = *(const float4*)
            &in[((long)(m & 31) * Tn + (m >> 5)) * INn + kt * 64 + cc];
        t[row][cc] = v.x; t[row][cc + 1] = v.y;
        t[row][cc + 2] = v.z; t[row][cc + 3] = v.w;
    }
    __syncthreads();
    unsigned short* dst = Abf + (long)(mtile * 4 + kt) * 8192;
#pragma unroll
    for (int j = 0; j < 4; ++j) {
        int q = tid + 256 * j;
        int kq = q >> 7, row = q & 127;
        short8v o;
#pragma unroll
        for (int i = 0; i < 8; ++i) o[i] = (short)f2bf(t[row][kq * 8 + i]);
        *(short8v*)&dst[(long)q * 8] = o;
    }
}

// ---------------------------------------------------------------------------
// Weight [K][NG] fp32 -> blocked bf16 B^T tiles [ntile][KT_][kq 8][n 64][e 8]
// ---------------------------------------------------------------------------
template<int KT_, int NG>
__global__ __launch_bounds__(256) void cvt_b(
    const float* __restrict__ Wg, unsigned short* __restrict__ Bb)
{
    int c = blockIdx.x * 256 + threadIdx.x;
    int n = c & 63;
    int c2 = c >> 6;
    int kq = c2 & 7;
    int c3 = c2 >> 3;
    int kt = c3 % KT_, ntile = c3 / KT_;
    short8v o;
#pragma unroll
    for (int i = 0; i < 8; ++i)
        o[i] = (short)f2bf(Wg[(long)(kt * 64 + kq * 8 + i) * NG + ntile * 64 + n]);
    *(short8v*)&Bb[(long)c * 8] = o;
}

// ---------------------------------------------------------------------------
// W_lat [k][h] fp32 -> Wq [h][k] fp8 e4m3 (transposed), 32x32 LDS tiles
// ---------------------------------------------------------------------------
__global__ __launch_bounds__(256) void wlat_cvt(
    const float* __restrict__ W, unsigned char* __restrict__ Wq)
{
    __shared__ float tile[32][33];
    const int tid = threadIdx.x;
    const int bx = blockIdx.x & 15, by = blockIdx.x >> 4;
    const int x = tid & 31, y = tid >> 5;
#pragma unroll
    for (int j = 0; j < 4; ++j)
        tile[y + j * 8][x] = W[(long)(by * 32 + y + j * 8) * Hn + bx * 32 + x];
    __syncthreads();
#pragma unroll
    for (int j = 0; j < 4; ++j)
        Wq[(long)(bx * 32 + y + j * 8) * Hn + by * 32 + x] =
            f2e4m3(tile[x][y + j * 8]);
}

// ---------------------------------------------------------------------------
// bf16 MFMA GEMM: 128x64 tile, BK=64, 256 thr (4 waves).  (ph1 / ph3)
// ---------------------------------------------------------------------------
template<int KT, bool OUT_BT, bool BIAS>
__global__ __launch_bounds__(256) void gemm_mfma(
    const unsigned short* __restrict__ A, const unsigned short* __restrict__ Bm,
    float* __restrict__ C, const float* __restrict__ bias, int N)
{
    __shared__ unsigned short Asl[2][8192];
    __shared__ unsigned short Bsl[2][4096];

    const int tid = threadIdx.x, lane = tid & 63, w = tid >> 6;
    const int ntile = blockIdx.x, mtile = blockIdx.y;
    const unsigned short* Abase = A + (long)mtile * KT * 8192;
    const unsigned short* Bbase = Bm + (long)ntile * KT * 4096;

    auto stageA = [&](int kt, int buf) {
#pragma unroll
        for (int j = 0; j < 4; ++j) {
            int c = tid + 256 * j;
            gl_lds16(Abase + (long)kt * 8192 + (long)c * 8, &Asl[buf][c * 8]);
        }
    };
    auto stageB = [&](int kt, int buf) {
#pragma unroll
        for (int j = 0; j < 2; ++j) {
            int c = tid + 256 * j;
            gl_lds16(Bbase + (long)kt * 4096 + (long)c * 8, &Bsl[buf][c * 8]);
        }
    };

    f32x4 acc[2][4] = {};
    stageA(0, 0); stageB(0, 0);
    int cur = 0;
#pragma unroll
    for (int kt = 0; kt < KT; ++kt) {
        __syncthreads();
        if (kt + 1 < KT) { stageA(kt + 1, cur ^ 1); stageB(kt + 1, cur ^ 1); }
#pragma unroll
        for (int ks = 0; ks < 2; ++ks) {
            const int kq = ks * 4 + (lane >> 4);
            short8v bfr[4];
#pragma unroll
            for (int nt = 0; nt < 4; ++nt)
                bfr[nt] = *(const short8v*)
                    &Bsl[cur][kq * 512 + (nt * 16 + (lane & 15)) * 8];
#pragma unroll
            for (int mt = 0; mt < 2; ++mt) {
                short8v afr = *(const short8v*)
                    &Asl[cur][kq * 1024 + (w * 32 + mt * 16 + (lane & 15)) * 8];
#pragma unroll
                for (int nt = 0; nt < 4; ++nt)
                    acc[mt][nt] = __builtin_amdgcn_mfma_f32_16x16x32_bf16(
                        afr, bfr[nt], acc[mt][nt], 0, 0, 0);
            }
        }
        cur ^= 1;
    }
#pragma unroll
    for (int mt = 0; mt < 2; ++mt)
#pragma unroll
        for (int r = 0; r < 4; ++r) {
            int row = mtile * 128 + w * 32 + mt * 16 + (lane >> 4) * 4 + r;
            long crow = OUT_BT ? ((long)(row & 31) * Tn + (row >> 5)) * N
                               : (long)row * N;
#pragma unroll
            for (int nt = 0; nt < 4; ++nt) {
                int col = ntile * 64 + nt * 16 + (lane & 15);
                float v = acc[mt][nt][r];
                if (BIAS) v += bias[col];
                C[crow + col] = v;
            }
        }
}

// ---------------------------------------------------------------------------
// Phase 2: 64 blocks (b = bid&31, half = bid>>5), 512 threads (8 waves).
// LDS: W slice [256 n][512 k] fp8 (128 KB, resident), A own-half [32][256]
// fp8, Sy [20][264] bf16. Wave w owns n-cols [w*32,(w+1)*32).
// Per stage k: poll partner flag>=k (acquire), read partner A-half from its
// global export slot (k-1)&1, GEMM (own half LDS + partner half regs),
// epilogue->Sy, barrier, ew (tid<256, h=h0+tid) -> A_lds own + export + F3,
// barrier, release flag=k+1.
// ---------------------------------------------------------------------------
__global__ __launch_bounds__(512) void phase2_pair(
    const unsigned char* __restrict__ Wq,    // [512 h][512 k] fp8
    const float* __restrict__ SYN,
    unsigned short* __restrict__ F3,         // ph3 blocked layout
    unsigned char* __restrict__ Gx,          // [64 bid][2 slot][32 t][256] fp8
    int* __restrict__ flags,                 // [64], memset 0 per launch
    const float* __restrict__ tkm, const float* __restrict__ thr,
    const float* __restrict__ aamp, const float* __restrict__ tascr,
    const float* __restrict__ tkasc)
{
    __shared__ unsigned char Wl[256 * 512];   // 128 KB
    __shared__ unsigned char Al[32 * 256];    // 8 KB (own k-half)
    __shared__ unsigned short Sy[DELAY][264]; // 10.3 KB

    const int tid = threadIdx.x, lane = tid & 63, w = tid >> 6;
    const int bid = blockIdx.x;
    const int b = bid & 31, half = bid >> 5;
    const int pb = bid ^ 32;                  // partner block
    const int h0 = half * 256;

    // ---- stage W slice into LDS (once), 16B-chunk-preserving swizzle <<4
#pragma unroll
    for (int i = 0; i < 16; ++i) {
        int c = tid + 512 * i;                // 16B chunk id, 8192 total
        int n = c >> 5, cc = c & 31;
        uint4 v = *(const uint4*)&Wq[(long)(h0 + n) * Hn + cc * 16];
        *(uint4*)(&Wl[(unsigned)(n * 512 + cc * 16) ^ ((unsigned)(n & 7) << 4)]) = v;
    }
    // zero A pad rows 20..31 (never written again; epilogue discards rows>=20)
    if (tid < 192)
        *(uint4*)(&Al[20 * 256 + tid * 16]) = make_uint4(0u, 0u, 0u, 0u);

    // ---- ew params (tid<256): h = h0 + tid
    const int h = h0 + tid;
    float dkm=0, th=0, am0=0, am1=0, rr0=0, rr1=0, dk0=0, dk1=0, kR=0;
    if (tid < 256) {
        dkm = sigmoidf_(tkm[h]);
        th  = thr[h];
        am0 = aamp[h];      am1 = aamp[Hn + h];
        rr0 = 1.f - 2.f * sigmoidf_(tascr[h]);
        rr1 = 1.f - 2.f * sigmoidf_(tascr[Hn + h]);
        dk0 = sigmoidf_(tkasc[h]);
        dk1 = sigmoidf_(tkasc[Hn + h]);
        kR  = dkm * Rc;
    }
    float volt = 0.f, fir = 0.f, a0s = 0.f, a1s = 0.f;
    const long f3_h = ((long)(h >> 6) * 8 + ((h >> 3) & 7)) * 1024 + (h & 7);

    // frag address invariants
    const int g8 = (lane >> 4) * 8;
    const int row0 = lane & 15, row1 = 16 + (lane & 15);
    const unsigned a0b = (unsigned)(row0 * 256 + g8), a0s_ = (unsigned)((row0 & 7) << 4);
    const unsigned a1b = (unsigned)(row1 * 256 + g8), a1s_ = (unsigned)((row1 & 7) << 4);
    const int n0 = w * 32 + (lane & 15), n1 = n0 + 16;
    const unsigned b0b = (unsigned)(n0 * 512 + g8), b0s_ = (unsigned)((n0 & 7) << 4);
    const unsigned b1b = (unsigned)(n1 * 512 + g8), b1s_ = (unsigned)((n1 & 7) << 4);
    const int ownKt0 = half * 8, parKt0 = 8 - half * 8;

    __syncthreads();

#pragma unroll 1
    for (int k = 0; k < NBLK; ++k) {
        // ff loads early (independent of poll/GEMM)
        float ff[DELAY];
        if (tid < 256) {
            const float* synk = SYN + (long)k * DELAY * BH + (long)b * Hn + h;
#pragma unroll
            for (int s = 0; s < DELAY; ++s)
                ff[s] = synk[(long)s * BH];
        }

        if (k > 0) {
            // acquire partner's stage-(k-1) export
            while (__hip_atomic_load(&flags[pb], __ATOMIC_ACQUIRE,
                                     __HIP_MEMORY_SCOPE_AGENT) < k) { }
            const unsigned char* gp = Gx + ((long)pb * 2 + ((k - 1) & 1)) * 8192;
            long long pa0[8], pa1[8];
#pragma unroll
            for (int kp = 0; kp < 8; ++kp) {
                pa0[kp] = *(const long long*)(gp + row0 * 256 + kp * 32 + g8);
                pa1[kp] = *(const long long*)(gp + row1 * 256 + kp * 32 + g8);
            }

            f32x4 acc00 = {}, acc01 = {}, acc10 = {}, acc11 = {};
            // own half: A from LDS
#pragma unroll
            for (int ktl = 0; ktl < 8; ++ktl) {
                long long af0 = *(const long long*)(Al + ((a0b + ktl * 32) ^ a0s_));
                long long af1 = *(const long long*)(Al + ((a1b + ktl * 32) ^ a1s_));
                int kt = ownKt0 + ktl;
                long long bf0 = *(const long long*)(Wl + ((b0b + kt * 32) ^ b0s_));
                long long bf1 = *(const long long*)(Wl + ((b1b + kt * 32) ^ b1s_));
                acc00 = __builtin_amdgcn_mfma_f32_16x16x32_fp8_fp8(af0, bf0, acc00, 0, 0, 0);
                acc01 = __builtin_amdgcn_mfma_f32_16x16x32_fp8_fp8(af0, bf1, acc01, 0, 0, 0);
                acc10 = __builtin_amdgcn_mfma_f32_16x16x32_fp8_fp8(af1, bf0, acc10, 0, 0, 0);
                acc11 = __builtin_amdgcn_mfma_f32_16x16x32_fp8_fp8(af1, bf1, acc11, 0, 0, 0);
            }
            // partner half: A from regs (global loads above)
#pragma unroll
            for (int kp = 0; kp < 8; ++kp) {
                int kt = parKt0 + kp;
                long long bf0 = *(const long long*)(Wl + ((b0b + kt * 32) ^ b0s_));
                long long bf1 = *(const long long*)(Wl + ((b1b + kt * 32) ^ b1s_));
                acc00 = __builtin_amdgcn_mfma_f32_16x16x32_fp8_fp8(pa0[kp], bf0, acc00, 0, 0, 0);
                acc01 = __builtin_amdgcn_mfma_f32_16x16x32_fp8_fp8(pa0[kp], bf1, acc01, 0, 0, 0);
                acc10 = __builtin_amdgcn_mfma_f32_16x16x32_fp8_fp8(pa1[kp], bf0, acc10, 0, 0, 0);
                acc11 = __builtin_amdgcn_mfma_f32_16x16x32_fp8_fp8(pa1[kp], bf1, acc11, 0, 0, 0);
            }
            // epilogue -> Sy. C frag: col=lane&15, row=(lane>>4)*4+r
#pragma unroll
            for (int r = 0; r < 4; ++r) {
                int ra = (lane >> 4) * 4 + r;          // mt=0 rows 0..15
                if (ra < DELAY) {
                    Sy[ra][w * 32 + (lane & 15)]      = f2bf(acc00[r]);
                    Sy[ra][w * 32 + 16 + (lane & 15)] = f2bf(acc01[r]);
                }
                int rb = 16 + ra;                      // mt=1 rows 16..31
                if (rb < DELAY) {
                    Sy[rb][w * 32 + (lane & 15)]      = f2bf(acc10[r]);
                    Sy[rb][w * 32 + 16 + (lane & 15)] = f2bf(acc11[r]);
                }
            }
        }
        __syncthreads();   // Sy visible; all A_lds/Wl GEMM reads complete

        // ---- ew recurrence (tid<256), writes A_lds own + export + F3
        if (tid < 256) {
            unsigned char* gex = Gx + ((long)bid * 2 + (k & 1)) * 8192;
            const int mbase = k * DELAY * Bsz + b;
#pragma unroll
            for (int s = 0; s < DELAY; ++s) {
                float sv = ff[s];
                if (k > 0) sv += bf2f(Sy[s][tid]);
                a0s = a0s * (rr0 * fir * DTc + (1.f - dk0)) + am0 * fir * DTc;
                a1s = a1s * (rr1 * fir * DTc + (1.f - dk1)) + am1 * fir * DTc;
                volt = volt * (1.f - dkm - fir) + kR * (sv + a0s + a1s);
                fir = sigfast_(volt - th);
                unsigned char q = f2e4m3(fir);
                Al[(unsigned)(s * 256 + tid) ^ ((unsigned)(s & 7) << 4)] = q;
                gex[s * 256 + tid] = q;
                int m = mbase + s * Bsz;
                F3[(long)(m >> 7) * 65536 + f3_h + (long)(m & 127) * 8] = f2bf(fir);
            }
        }
        __syncthreads();   // drains all global stores (vmcnt 0) + LDS visible
        if (tid == 0)
            __hip_atomic_store(&flags[bid], k + 1, __ATOMIC_RELEASE,
                               __HIP_MEMORY_SCOPE_AGENT);
    }
}

extern "C" void kernel_launch(void* const* d_in, const int* in_sizes, int n_in,
                              void* d_out, int out_size, void* d_ws, size_t ws_size,
                              hipStream_t stream) {
    const float* input = (const float*)d_in[0];   // [B,T,IN]
    const float* w_iv  = (const float*)d_in[1];   // [IN,H]
    const float* w_lat = (const float*)d_in[2];   // [H,H]
    const float* thr   = (const float*)d_in[3];   // [1,H]
    const float* tkm   = (const float*)d_in[4];   // [1,H]
    const float* aamp  = (const float*)d_in[5];   // [A,1,H]
    const float* tascr = (const float*)d_in[6];   // [A,1,H]
    const float* tkasc = (const float*)d_in[7];   // [A,1,H]
    const float* outw  = (const float*)d_in[8];   // [H,OUT]
    const float* outb  = (const float*)d_in[9];   // [OUT]
    float* out = (float*)d_out;                   // [B,T,OUT]

    const size_t TBH = (size_t)Tn * BH;           // 16,384,000
    float* SYN           = (float*)d_ws;                  // [T][B][H] fp32
    unsigned short* F3   = (unsigned short*)(SYN + TBH);  // blocked bf16 F
    unsigned short* Abf  = F3 + TBH;                      // blocked bf16 input
    unsigned char* Wq    = (unsigned char*)(Abf + (size_t)8192 * 1000);
    unsigned short* Wivb = (unsigned short*)(Wq + (size_t)Hn * Hn);
    unsigned short* Wowb = Wivb + (size_t)INn * Hn;
    unsigned char* Gx    = (unsigned char*)(Wowb + (size_t)Hn * OUTn);
    int* flags           = (int*)(Gx + (size_t)64 * 2 * 8192);

    // flags must start at 0 every launch (graph-safe async memset)
    hipMemsetAsync(flags, 0, 64 * sizeof(int), stream);

    // Phase 0: conversions (independent)
    cvt_in<<<1000, 256, 0, stream>>>(input, Abf);
    cvt_b<4, 512><<<64, 256, 0, stream>>>(w_iv, Wivb);
    cvt_b<8, 128><<<32, 256, 0, stream>>>(outw, Wowb);
    wlat_cvt<<<256, 256, 0, stream>>>(w_lat, Wq);

    // Phase 1: SYN = input @ W_iv  (M=32000, N=512, K=256)
    gemm_mfma<4, false, false><<<dim3(8, 250), 256, 0, stream>>>(
        Abf, Wivb, SYN, nullptr, Hn);

    // Phase 2: 64 pair-blocks (2 per batch), W slice LDS-resident
    phase2_pair<<<64, 512, 0, stream>>>(Wq, SYN, F3, Gx, flags,
                                        tkm, thr, aamp, tascr, tkasc);

    // Phase 3: out = F @ out_w + out_b  (M=32000, N=128, K=512)
    gemm_mfma<8, true, true><<<dim3(2, 250), 256, 0, stream>>>(
        F3, Wowb, out, outb, OUTn);
}

// Round 13
// 385.795 us; speedup vs baseline: 1.8534x; 1.8534x over previous
//
#include <hip/hip_runtime.h>
#include <math.h>

// GLIFR (BNNFC) : B=32, T=1000, IN=256, H=512, OUT=128, A=2, DELAY=20
//  cvts: input->Abf (blocked bf16), W_iv/out_w -> blocked bf16, W_lat -> fp8
//  ph1: SYN(bf16) = input @ W_iv    (bf16 MFMA GEMM, blocked operands)
//  ph2: 32 independent blocks (one batch each), 512 thr = 8 waves. R13: the
//       ff-syn path goes through LDS (SynL double-buffer, global_load_lds
//       issued one stage ahead) -- R7..R12 showed a ~5us/stage wall common to
//       all W strategies; hypothesis: ff register prefetch was spilled/sunk,
//       putting HBM latency inside the serial ew chain. W as in R9.
//  ph3: out = F @ out_w + out_b     (bf16 MFMA GEMM)

constexpr int Bsz   = 32;
constexpr int Tn    = 1000;
constexpr int INn   = 256;
constexpr int Hn    = 512;
constexpr int OUTn  = 128;
constexpr int DELAY = 20;
constexpr int NBLK  = Tn / DELAY;   // 50
constexpr float DTc = 0.05f;
constexpr float Rc  = 0.1f;
constexpr int BH = Bsz * Hn;                  // 16384

typedef __attribute__((ext_vector_type(8))) short short8v;  // 8 bf16
typedef __attribute__((ext_vector_type(4))) float f32x4;

__device__ __forceinline__ float sigmoidf_(float x) {
    return 1.0f / (1.0f + expf(-x));
}
__device__ __forceinline__ float sigfast_(float x) {
    return __builtin_amdgcn_rcpf(1.0f + __builtin_amdgcn_exp2f(x * -1.44269504f));
}
__device__ __forceinline__ float bf2f(unsigned short u) {
    return __uint_as_float(((unsigned)u) << 16);
}
__device__ __forceinline__ unsigned short f2bf(float f) {
    unsigned x = __float_as_uint(f);
    return (unsigned short)((x + 0x7fff + ((x >> 16) & 1)) >> 16);  // RNE
}
// OCP e4m3fn encode, RNE, |x| small
__device__ __forceinline__ unsigned char f2e4m3(float x) {
    unsigned b = __float_as_uint(x);
    unsigned s = (b >> 31) << 7;
    b &= 0x7fffffffu;
    unsigned code;
    if (__uint_as_float(b) < 0.015625f) {
        code = (unsigned)__float2int_rn(__uint_as_float(b) * 512.0f);
    } else {
        unsigned r = b + 0x7ffffu + ((b >> 20) & 1);
        int e = (int)(r >> 23) - 127;
        code = (unsigned)(((e + 7) << 3) | ((r >> 20) & 7));
    }
    return (unsigned char)(s | code);
}
__device__ __forceinline__ void gl_lds16(const void* g, void* l) {
    __builtin_amdgcn_global_load_lds(
        (const __attribute__((address_space(1))) void*)g,
        (__attribute__((address_space(3))) void*)l, 16, 0, 0);
}

// ---------------------------------------------------------------------------
// input [B,T,IN] fp32 -> Abf blocked bf16 [mtile 250][kt 4][kq 8][row 128][e 8]
// ---------------------------------------------------------------------------
__global__ __launch_bounds__(256) void cvt_in(
    const float* __restrict__ in, unsigned short* __restrict__ Abf)
{
    __shared__ float t[128][65];
    const int tid = threadIdx.x;
    const int mtile = blockIdx.x >> 2, kt = blockIdx.x & 3;
    const int rr = tid >> 4, cc = (tid & 15) * 4;
#pragma unroll
    for (int j = 0; j < 8; ++j) {
        int row = j * 16 + rr;
        int m = mtile * 128 + row;
        float4 v = *(const float4*)
            &in[((long)(m & 31) * Tn + (m >> 5)) * INn + kt * 64 + cc];
        t[row][cc] = v.x; t[row][cc + 1] = v.y;
        t[row][cc + 2] = v.z; t[row][cc + 3] = v.w;
    }
    __syncthreads();
    unsigned short* dst = Abf + (long)(mtile * 4 + kt) * 8192;
#pragma unroll
    for (int j = 0; j < 4; ++j) {
        int q = tid + 256 * j;
        int kq = q >> 7, row = q & 127;
        short8v o;
#pragma unroll
        for (int i = 0; i < 8; ++i) o[i] = (short)f2bf(t[row][kq * 8 + i]);
        *(short8v*)&dst[(long)q * 8] = o;
    }
}

// ---------------------------------------------------------------------------
// Weight [K][NG] fp32 -> blocked bf16 B^T tiles [ntile][KT_][kq 8][n 64][e 8]
// ---------------------------------------------------------------------------
template<int KT_, int NG>
__global__ __launch_bounds__(256) void cvt_b(
    const float* __restrict__ Wg, unsigned short* __restrict__ Bb)
{
    int c = blockIdx.x * 256 + threadIdx.x;
    int n = c & 63;
    int c2 = c >> 6;
    int kq = c2 & 7;
    int c3 = c2 >> 3;
    int kt = c3 % KT_, ntile = c3 / KT_;
    short8v o;
#pragma unroll
    for (int i = 0; i < 8; ++i)
        o[i] = (short)f2bf(Wg[(long)(kt * 64 + kq * 8 + i) * NG + ntile * 64 + n]);
    *(short8v*)&Bb[(long)c * 8] = o;
}

// ---------------------------------------------------------------------------
// W_lat [k][h] fp32 -> Wq [h][k] fp8 e4m3 (transposed), 32x32 LDS tiles
// ---------------------------------------------------------------------------
__global__ __launch_bounds__(256) void wlat_cvt(
    const float* __restrict__ W, unsigned char* __restrict__ Wq)
{
    __shared__ float tile[32][33];
    const int tid = threadIdx.x;
    const int bx = blockIdx.x & 15, by = blockIdx.x >> 4;
    const int x = tid & 31, y = tid >> 5;
#pragma unroll
    for (int j = 0; j < 4; ++j)
        tile[y + j * 8][x] = W[(long)(by * 32 + y + j * 8) * Hn + bx * 32 + x];
    __syncthreads();
#pragma unroll
    for (int j = 0; j < 4; ++j)
        Wq[(long)(bx * 32 + y + j * 8) * Hn + by * 32 + x] =
            f2e4m3(tile[x][y + j * 8]);
}

// ---------------------------------------------------------------------------
// bf16 MFMA GEMM: 128x64 tile, BK=64, 256 thr (4 waves).
// CBF16: C written as bf16 (for SYN); else fp32.
// OUT_BT: C row m -> out[(m&31)*Tn + (m>>5)] (i.e. [B,T,N]); else C + m*N.
// ---------------------------------------------------------------------------
template<int KT, bool OUT_BT, bool BIAS, bool CBF16>
__global__ __launch_bounds__(256) void gemm_mfma(
    const unsigned short* __restrict__ A, const unsigned short* __restrict__ Bm,
    void* __restrict__ Cv, const float* __restrict__ bias, int N)
{
    __shared__ unsigned short Asl[2][8192];
    __shared__ unsigned short Bsl[2][4096];

    const int tid = threadIdx.x, lane = tid & 63, w = tid >> 6;
    const int ntile = blockIdx.x, mtile = blockIdx.y;
    const unsigned short* Abase = A + (long)mtile * KT * 8192;
    const unsigned short* Bbase = Bm + (long)ntile * KT * 4096;

    auto stageA = [&](int kt, int buf) {
#pragma unroll
        for (int j = 0; j < 4; ++j) {
            int c = tid + 256 * j;
            gl_lds16(Abase + (long)kt * 8192 + (long)c * 8, &Asl[buf][c * 8]);
        }
    };
    auto stageB = [&](int kt, int buf) {
#pragma unroll
        for (int j = 0; j < 2; ++j) {
            int c = tid + 256 * j;
            gl_lds16(Bbase + (long)kt * 4096 + (long)c * 8, &Bsl[buf][c * 8]);
        }
    };

    f32x4 acc[2][4] = {};
    stageA(0, 0); stageB(0, 0);
    int cur = 0;
#pragma unroll
    for (int kt = 0; kt < KT; ++kt) {
        __syncthreads();
        if (kt + 1 < KT) { stageA(kt + 1, cur ^ 1); stageB(kt + 1, cur ^ 1); }
#pragma unroll
        for (int ks = 0; ks < 2; ++ks) {
            const int kq = ks * 4 + (lane >> 4);
            short8v bfr[4];
#pragma unroll
            for (int nt = 0; nt < 4; ++nt)
                bfr[nt] = *(const short8v*)
                    &Bsl[cur][kq * 512 + (nt * 16 + (lane & 15)) * 8];
#pragma unroll
            for (int mt = 0; mt < 2; ++mt) {
                short8v afr = *(const short8v*)
                    &Asl[cur][kq * 1024 + (w * 32 + mt * 16 + (lane & 15)) * 8];
#pragma unroll
                for (int nt = 0; nt < 4; ++nt)
                    acc[mt][nt] = __builtin_amdgcn_mfma_f32_16x16x32_bf16(
                        afr, bfr[nt], acc[mt][nt], 0, 0, 0);
            }
        }
        cur ^= 1;
    }
#pragma unroll
    for (int mt = 0; mt < 2; ++mt)
#pragma unroll
        for (int r = 0; r < 4; ++r) {
            int row = mtile * 128 + w * 32 + mt * 16 + (lane >> 4) * 4 + r;
            long crow = OUT_BT ? ((long)(row & 31) * Tn + (row >> 5)) * N
                               : (long)row * N;
#pragma unroll
            for (int nt = 0; nt < 4; ++nt) {
                int col = ntile * 64 + nt * 16 + (lane & 15);
                float v = acc[mt][nt][r];
                if (BIAS) v += bias[col];
                if (CBF16) ((unsigned short*)Cv)[crow + col] = f2bf(v);
                else       ((float*)Cv)[crow + col] = v;
            }
        }
}

// ---------------------------------------------------------------------------
// Phase 2: 32 independent blocks (one per batch b), 512 threads (8 waves).
// W fp8 fragments nominally in regs (R9 behavior: allocator streams them --
// accepted for this round). ff-syn via SynL LDS double-buffer, prefetched one
// stage ahead with global_load_lds (1 row = 1 instr). ew reads LDS only.
// ---------------------------------------------------------------------------
__global__ __launch_bounds__(512) void phase2_bpart(
    const unsigned char* __restrict__ Wq,    // [512 n][512 k] fp8
    const unsigned short* __restrict__ SYN,  // [T][B][H] bf16
    unsigned short* __restrict__ F3,         // ph3 blocked layout
    const float* __restrict__ tkm, const float* __restrict__ thr,
    const float* __restrict__ aamp, const float* __restrict__ tascr,
    const float* __restrict__ tkasc)
{
    __shared__ unsigned char A_lds[2][32 * 512];     // 2 x 16 KB fp8, swizzled
    __shared__ unsigned short Sy[DELAY][520];        // 20.3 KB bf16
    __shared__ unsigned short SynL[2][DELAY][512];   // 40 KB bf16 (ff prefetch)

    const int tid = threadIdx.x;
    const int b = blockIdx.x;
    const int lane = tid & 63, w = tid >> 6;

    // zero both A buffers (covers pad rows 20..31 forever)
#pragma unroll
    for (int j = 0; j < 4; ++j)
        *(uint4*)(&A_lds[0][0] + (j * 512 + tid) * 16) = make_uint4(0u,0u,0u,0u);

    // ---- W fragments -> registers (once; R9 semantics).
    long long wreg[16][4];
#pragma unroll
    for (int kt = 0; kt < 16; ++kt)
#pragma unroll
        for (int nt = 0; nt < 4; ++nt) {
            int n = w * 64 + nt * 16 + (lane & 15);
            int kk = kt * 32 + (lane >> 4) * 8;
            wreg[kt][nt] = *(const long long*)&Wq[(long)n * Hn + kk];
        }

    // ---- per-thread ew params: h = tid (computed once)
    const int h = tid;
    const float dkm  = sigmoidf_(tkm[h]);
    const float th   = thr[h];
    const float am0  = aamp[h],       am1 = aamp[Hn + h];
    const float rr0  = 1.f - 2.f * sigmoidf_(tascr[h]);
    const float rr1  = 1.f - 2.f * sigmoidf_(tascr[Hn + h]);
    const float dk0  = sigmoidf_(tkasc[h]);
    const float dk1  = sigmoidf_(tkasc[Hn + h]);
    const float kR   = dkm * Rc;
    float volt = 0.f, fir = 0.f, a0 = 0.f, a1 = 0.f;

    // F3 per-thread invariants
    const long f3_h = ((long)(h >> 6) * 8 + ((h >> 3) & 7)) * 1024 + (h & 7);

    // A-frag byte offsets (row = mt*16 + (lane&15); 8B chunk (lane>>4)*8;
    // XOR swizzle bits 3..5 with row&7)
    const int ar0 = lane & 15, ar1 = 16 + (lane & 15);
    const unsigned a0base = (unsigned)(ar0 * 512 + (lane >> 4) * 8);
    const unsigned a1base = (unsigned)(ar1 * 512 + (lane >> 4) * 8);
    const unsigned swz0 = (unsigned)((ar0 & 7) << 3);
    const unsigned swz1 = (unsigned)((ar1 & 7) << 3);

    // ff-syn prefetch: 20 rows, 1 global_load_lds each (1 KB = 64 lanes x 16B).
    // wave w issues rows 2w, 2w+1; waves 0..3 also issue rows 16..19.
    auto prefetchSyn = [&](int k2) {
        const int buf = k2 & 1;
        const unsigned short* base = SYN + (long)k2 * DELAY * BH + (long)b * Hn
                                     + lane * 8;
        int r0 = w * 2;
        gl_lds16(base + (long)r0 * BH,       &SynL[buf][r0][0]);
        gl_lds16(base + (long)(r0 + 1) * BH, &SynL[buf][r0 + 1][0]);
        if (w < 4)
            gl_lds16(base + (long)(16 + w) * BH, &SynL[buf][16 + w][0]);
    };

    prefetchSyn(0);
    __syncthreads();   // drains prologue loads; A_lds zeros visible

#pragma unroll 1
    for (int k = 0; k < NBLK; ++k) {
        // issue NEXT stage's ff prefetch first: lands during GEMM+ew
        if (k + 1 < NBLK) prefetchSyn(k + 1);

        if (k > 0) {
            const unsigned char* Ab = &A_lds[k & 1][0];
            f32x4 acc[2][4] = {};
#pragma unroll
            for (int kt = 0; kt < 16; ++kt) {
                long long afr0 = *(const long long*)(Ab + ((a0base + kt * 32) ^ swz0));
                long long afr1 = *(const long long*)(Ab + ((a1base + kt * 32) ^ swz1));
#pragma unroll
                for (int nt = 0; nt < 4; ++nt) {
                    acc[0][nt] = __builtin_amdgcn_mfma_f32_16x16x32_fp8_fp8(
                        afr0, wreg[kt][nt], acc[0][nt], 0, 0, 0);
                    acc[1][nt] = __builtin_amdgcn_mfma_f32_16x16x32_fp8_fp8(
                        afr1, wreg[kt][nt], acc[1][nt], 0, 0, 0);
                }
            }
            // epilogue -> Sy (own strip, bf16). C frag: col=lane&15,
            // row=(lane>>4)*4+r
#pragma unroll
            for (int mt = 0; mt < 2; ++mt)
#pragma unroll
                for (int r = 0; r < 4; ++r) {
                    int row = mt * 16 + (lane >> 4) * 4 + r;
                    if (row < DELAY) {
#pragma unroll
                        for (int nt = 0; nt < 4; ++nt)
                            Sy[row][w * 64 + nt * 16 + (lane & 15)]
                                = f2bf(acc[mt][nt][r]);
                    }
                }
        }

        // ---- elementwise recurrence; ff from SynL (this stage's buffer was
        // prefetched last stage; stage-end barrier drained its loads).
        unsigned char* An = &A_lds[(k + 1) & 1][0];
        const int mbase = k * DELAY * Bsz + b;
        const unsigned short* SynR = &SynL[k & 1][0][0];
#pragma unroll
        for (int s = 0; s < DELAY; ++s) {
            float sv = bf2f(SynR[s * 512 + h]);
            if (k > 0) sv += bf2f(Sy[s][h]);
            a0 = a0 * (rr0 * fir * DTc + (1.f - dk0)) + am0 * fir * DTc;
            a1 = a1 * (rr1 * fir * DTc + (1.f - dk1)) + am1 * fir * DTc;
            volt = volt * (1.f - dkm - fir) + kR * (sv + a0 + a1);
            fir = sigfast_(volt - th);
            An[(unsigned)(s * 512 + h) ^ ((unsigned)(s & 7) << 3)] = f2e4m3(fir);
            int m = mbase + s * Bsz;
            F3[(long)(m >> 7) * 65536 + f3_h + (long)(m & 127) * 8] = f2bf(fir);
        }
        __syncthreads();   // A_lds[(k+1)&1] + SynL[(k+1)&1] ready for next stage
    }
}

extern "C" void kernel_launch(void* const* d_in, const int* in_sizes, int n_in,
                              void* d_out, int out_size, void* d_ws, size_t ws_size,
                              hipStream_t stream) {
    const float* input = (const float*)d_in[0];   // [B,T,IN]
    const float* w_iv  = (const float*)d_in[1];   // [IN,H]
    const float* w_lat = (const float*)d_in[2];   // [H,H]
    const float* thr   = (const float*)d_in[3];   // [1,H]
    const float* tkm   = (const float*)d_in[4];   // [1,H]
    const float* aamp  = (const float*)d_in[5];   // [A,1,H]
    const float* tascr = (const float*)d_in[6];   // [A,1,H]
    const float* tkasc = (const float*)d_in[7];   // [A,1,H]
    const float* outw  = (const float*)d_in[8];   // [H,OUT]
    const float* outb  = (const float*)d_in[9];   // [OUT]
    float* out = (float*)d_out;                   // [B,T,OUT]

    const size_t TBH = (size_t)Tn * BH;           // 16,384,000
    unsigned short* SYNb = (unsigned short*)d_ws;         // [T][B][H] bf16
    unsigned short* F3   = SYNb + TBH;                    // blocked bf16 F
    unsigned short* Abf  = F3 + TBH;                      // blocked bf16 input
    unsigned char* Wq    = (unsigned char*)(Abf + (size_t)8192 * 1000);
    unsigned short* Wivb = (unsigned short*)(Wq + (size_t)Hn * Hn);
    unsigned short* Wowb = Wivb + (size_t)INn * Hn;

    // Phase 0: conversions (independent)
    cvt_in<<<1000, 256, 0, stream>>>(input, Abf);
    cvt_b<4, 512><<<64, 256, 0, stream>>>(w_iv, Wivb);
    cvt_b<8, 128><<<32, 256, 0, stream>>>(outw, Wowb);
    wlat_cvt<<<256, 256, 0, stream>>>(w_lat, Wq);

    // Phase 1: SYN(bf16) = input @ W_iv  (M=32000, N=512, K=256)
    gemm_mfma<4, false, false, true><<<dim3(8, 250), 256, 0, stream>>>(
        Abf, Wivb, SYNb, nullptr, Hn);

    // Phase 2: 32 independent per-batch blocks, all 50 stages internal
    phase2_bpart<<<32, 512, 0, stream>>>(Wq, SYNb, F3,
                                         tkm, thr, aamp, tascr, tkasc);

    // Phase 3: out = F @ out_w + out_b  (M=32000, N=128, K=512)
    gemm_mfma<8, true, true, false><<<dim3(2, 250), 256, 0, stream>>>(
        F3, Wowb, out, outb, OUTn);
}